// Round 3
// baseline (318.334 us; speedup 1.0000x reference)
//
#include <hip/hip_runtime.h>

#define N_NODES 1024
#define C_CH    128
#define L_ELL   16
#define N_ELEM  10
#define K3      11
#define K2      4

// named-register T3 fragment: t3_J_Q = T3[m][i1][4g+J][4Q..4Q+3]
#define DECL_T3 \
  float4 t3_0_0, t3_0_1, t3_0_2, t3_0_3, \
         t3_1_0, t3_1_1, t3_1_2, t3_1_3, \
         t3_2_0, t3_2_1, t3_2_2, t3_2_3, \
         t3_3_0, t3_3_1, t3_3_2, t3_3_3;

#define LOADT3(J, Q) \
  t3_##J##_##Q = *(const float4*)&T3s[(i1 * 256 + (4 * g + J) * 16 + Q * 4) ^ xorv];

#define FMA4(J, Q, XV)                                  \
  a##J = fmaf(t3_##J##_##Q.x, XV.x, a##J);              \
  a##J = fmaf(t3_##J##_##Q.y, XV.y, a##J);              \
  a##J = fmaf(t3_##J##_##Q.z, XV.z, a##J);              \
  a##J = fmaf(t3_##J##_##Q.w, XV.w, a##J);

__global__ __launch_bounds__(256) void sym_contract_kernel(
    const float* __restrict__ node_feats,   // [N, C, 16]
    const float* __restrict__ node_attrs,   // [N, 10]
    const float* __restrict__ U03, const float* __restrict__ W03,
    const float* __restrict__ U02, const float* __restrict__ W02,
    const float* __restrict__ U01, const float* __restrict__ W01,
    const float* __restrict__ U13, const float* __restrict__ W13,
    const float* __restrict__ U12, const float* __restrict__ W12,
    const float* __restrict__ U11, const float* __restrict__ W11,
    float* __restrict__ feats_out)          // [N, C*4] pre-linear (= d_out)
{
  __shared__ float T3s[4096];               // one m-slice, XOR-swizzled
  __shared__ unsigned short nodelist[N_NODES];
  __shared__ float wrow[32];
  __shared__ int cnt;

  const int e    = blockIdx.x / C_CH;
  const int c    = blockIdx.x % C_CH;
  const int tid  = threadIdx.x;
  const int m    = tid >> 6;                // wave id = output slot
  const int lane = tid & 63;
  const int g    = lane >> 4;               // i2-quad
  const int i1   = lane & 15;

  if (tid == 0) cnt = 0;
  if (tid < 32) {
    float v;
    if (tid < 11)       v = W03[(e * K3 + tid) * C_CH + c];
    else if (tid < 15)  v = W02[(e * K2 + (tid - 11)) * C_CH + c];
    else if (tid == 15) v = W01[e * C_CH + c];
    else if (tid < 27)  v = W13[(e * K3 + (tid - 16)) * C_CH + c];
    else if (tid < 31)  v = W12[(e * K2 + (tid - 27)) * C_CH + c];
    else                v = W11[e * C_CH + c];
    wrow[tid] = v;
  }
  __syncthreads();

  // node list for this element
  for (int b = tid; b < N_NODES; b += 256)
    if (node_attrs[b * N_ELEM + e] > 0.5f) {
      int p = atomicAdd(&cnt, 1);
      nodelist[p] = (unsigned short)b;
    }

  // --- T2, T1 straight into registers ---
  float t2[4];
  {
    const int wb = (m == 0) ? 11 : 27;
    float w2v[4];
    #pragma unroll
    for (int k = 0; k < 4; ++k) w2v[k] = wrow[wb + k];
    #pragma unroll
    for (int j = 0; j < 4; ++j) {
      const int r2 = i1 * 16 + 4 * g + j;
      const float4 u2 = (m == 0)
          ? *(const float4*)(U02 + r2 * K2)
          : *(const float4*)(U12 + ((m - 1) * 256 + r2) * K2);
      t2[j] = u2.x * w2v[0] + u2.y * w2v[1] + u2.z * w2v[2] + u2.w * w2v[3];
    }
  }
  const float t1 = (m == 0) ? U01[i1] * wrow[15]
                            : U11[(m - 1) * 16 + i1] * wrow[31];

  // --- T3 into named registers: build one m-slice at a time in LDS ---
  DECL_T3
  const int xorv = (i1 & 7) << 2;
  for (int s = 0; s < 4; ++s) {
    __syncthreads();                         // previous slice fully consumed
    const int wb = (s == 0) ? 0 : 16;
    float wk[K3];
    #pragma unroll
    for (int k = 0; k < K3; ++k) wk[k] = wrow[wb + k];
    const float* U3 = (s == 0) ? U03 : (U13 + (size_t)(s - 1) * 4096 * K3);
    for (int w = tid; w < 4096; w += 256) {
      const float* up = U3 + (size_t)w * K3;
      float acc = 0.f;
      #pragma unroll
      for (int k = 0; k < K3; ++k) acc = fmaf(up[k], wk[k], acc);
      T3s[w ^ (((w >> 8) & 7) << 2)] = acc;
    }
    __syncthreads();
    if (m == s) {
      LOADT3(0,0) LOADT3(0,1) LOADT3(0,2) LOADT3(0,3)
      LOADT3(1,0) LOADT3(1,1) LOADT3(1,2) LOADT3(1,3)
      LOADT3(2,0) LOADT3(2,1) LOADT3(2,2) LOADT3(2,3)
      LOADT3(3,0) LOADT3(3,1) LOADT3(3,2) LOADT3(3,3)
    }
  }
  __syncthreads();

  // --- phase B: loop nodes, all operands register/L1-resident ---
  const int total = cnt;
  for (int n = 0; n < total; ++n) {
    const int b = nodelist[n];
    const float* xr = node_feats + ((size_t)b * C_CH + c) * L_ELL;
    const float4 xq0 = ((const float4*)xr)[0];   // wave-uniform addr -> L1 broadcast
    const float4 xq1 = ((const float4*)xr)[1];
    const float4 xq2 = ((const float4*)xr)[2];
    const float4 xq3 = ((const float4*)xr)[3];
    const float4 xg  = ((const float4*)xr)[g];   // lane-dep, one 64B line
    const float  xi  = xr[i1];

    float a0 = t2[0], a1 = t2[1], a2 = t2[2], a3 = t2[3];
    FMA4(0, 0, xq0) FMA4(0, 1, xq1) FMA4(0, 2, xq2) FMA4(0, 3, xq3)
    FMA4(1, 0, xq0) FMA4(1, 1, xq1) FMA4(1, 2, xq2) FMA4(1, 3, xq3)
    FMA4(2, 0, xq0) FMA4(2, 1, xq1) FMA4(2, 2, xq2) FMA4(2, 3, xq3)
    FMA4(3, 0, xq0) FMA4(3, 1, xq1) FMA4(3, 2, xq2) FMA4(3, 3, xq3)

    float p = a0 * xg.x + a1 * xg.y + a2 * xg.z + a3 * xg.w;
    p += __shfl_xor(p, 16);
    p += __shfl_xor(p, 32);                  // sum over i2-quads g
    float r = (p + t1) * xi;
    r += __shfl_xor(r, 1);
    r += __shfl_xor(r, 2);
    r += __shfl_xor(r, 4);
    r += __shfl_xor(r, 8);                   // sum over i1
    if (lane == 0)
      feats_out[(size_t)b * 512 + c * 4 + m] = r;
  }
}

__global__ __launch_bounds__(256) void linear_kernel(
    const float* __restrict__ sc,
    const float* __restrict__ lin0,
    const float* __restrict__ lin1,
    float* __restrict__ io)             // d_out, in-place per-row
{
  __shared__ float f[512];              // [c][m]
  const int b   = blockIdx.x;
  const int tid = threadIdx.x;
  const float* row = io + (size_t)b * 512;
  if (tid < 128) ((float4*)f)[tid] = ((const float4*)row)[tid];
  __syncthreads();
  const float inv_sqrt_c = 0.088388347648318447f;   // 1/sqrt(128)
  #pragma unroll
  for (int rep = 0; rep < 2; ++rep) {
    const int o = tid + rep * 256;
    float acc = 0.f;
    if (o < 128) {
      const int fo = o;
      #pragma unroll 4
      for (int ci = 0; ci < 128; ++ci) acc += f[ci * 4] * lin0[ci * 128 + fo];
    } else {
      const int oo = o - 128;
      const int fo = oo / 3;
      const int dd = oo - fo * 3;
      #pragma unroll 4
      for (int ci = 0; ci < 128; ++ci) acc += f[ci * 4 + 1 + dd] * lin1[ci * 128 + fo];
    }
    io[(size_t)b * 512 + o] = acc * inv_sqrt_c + sc[(size_t)b * 512 + o];
  }
}

extern "C" void kernel_launch(void* const* d_in, const int* in_sizes, int n_in,
                              void* d_out, int out_size, void* d_ws, size_t ws_size,
                              hipStream_t stream) {
  const float* node_feats = (const float*)d_in[0];
  const float* sc         = (const float*)d_in[1];
  const float* node_attrs = (const float*)d_in[2];
  const float* U01  = (const float*)d_in[3];
  const float* W01  = (const float*)d_in[4];
  const float* U02  = (const float*)d_in[5];
  const float* W02  = (const float*)d_in[6];
  const float* U03  = (const float*)d_in[7];
  const float* W03  = (const float*)d_in[8];
  const float* lin0 = (const float*)d_in[9];
  const float* U11  = (const float*)d_in[10];
  const float* W11  = (const float*)d_in[11];
  const float* U12  = (const float*)d_in[12];
  const float* W12  = (const float*)d_in[13];
  const float* U13  = (const float*)d_in[14];
  const float* W13  = (const float*)d_in[15];
  const float* lin1 = (const float*)d_in[16];
  float* out = (float*)d_out;

  sym_contract_kernel<<<N_ELEM * C_CH, 256, 0, stream>>>(
      node_feats, node_attrs,
      U03, W03, U02, W02, U01, W01,
      U13, W13, U12, W12, U11, W11, out);
  linear_kernel<<<N_NODES, 256, 0, stream>>>(sc, lin0, lin1, out);
}

// Round 4
// 172.464 us; speedup vs baseline: 1.8458x; 1.8458x over previous
//
#include <hip/hip_runtime.h>

#define N_NODES 1024
#define C_CH    128
#define N_ELEM  10
#define K3      11
#define K2      4

__global__ __launch_bounds__(512) void sym_contract_kernel(
    const float* __restrict__ node_feats,   // [N, C, 16]
    const float* __restrict__ node_attrs,   // [N, 10]
    const float* __restrict__ U03, const float* __restrict__ W03,
    const float* __restrict__ U02, const float* __restrict__ W02,
    const float* __restrict__ U01, const float* __restrict__ W01,
    const float* __restrict__ U13, const float* __restrict__ W13,
    const float* __restrict__ U12, const float* __restrict__ W12,
    const float* __restrict__ U11, const float* __restrict__ W11,
    float* __restrict__ feats_out)          // [N, C*4] pre-linear (= d_out)
{
  __shared__ float T3s[4 * 4096];           // [m][i1][i2][i3] linear; broadcast reads
  __shared__ float T2s[4 * 256];            // [m][i1][i2]
  __shared__ float T1s[4 * 16];             // [m][i1]
  __shared__ float Xl[2][16][64];           // per-lane x stash for dynamic x[i1]
  __shared__ unsigned short nodelist[N_NODES];
  __shared__ float wrow[32];
  __shared__ int cnt;

  const int e   = blockIdx.x / C_CH;
  const int c   = blockIdx.x % C_CH;
  const int tid = threadIdx.x;

  if (tid == 0) cnt = 0;
  if (tid < 32) {
    float v;
    if (tid < 11)       v = W03[(e * K3 + tid) * C_CH + c];
    else if (tid < 15)  v = W02[(e * K2 + (tid - 11)) * C_CH + c];
    else if (tid == 15) v = W01[e * C_CH + c];
    else if (tid < 27)  v = W13[(e * K3 + (tid - 16)) * C_CH + c];
    else if (tid < 31)  v = W12[(e * K2 + (tid - 27)) * C_CH + c];
    else                v = W11[e * C_CH + c];
    wrow[tid] = v;
  }
  __syncthreads();

  // --- node list for this element ---
  for (int b = tid; b < N_NODES; b += 512)
    if (node_attrs[b * N_ELEM + e] > 0.5f) {
      int p = atomicAdd(&cnt, 1);
      nodelist[p] = (unsigned short)b;
    }

  // --- build T3 (all 4 m-slices, linear layout) ---
  for (int s = 0; s < 4; ++s) {
    const int wb = (s == 0) ? 0 : 16;
    float wk[K3];
    #pragma unroll
    for (int k = 0; k < K3; ++k) wk[k] = wrow[wb + k];
    const float* U3 = (s == 0) ? U03 : (U13 + (size_t)(s - 1) * 4096 * K3);
    for (int w = tid; w < 4096; w += 512) {
      const float* up = U3 + (size_t)w * K3;
      float acc = 0.f;
      #pragma unroll
      for (int k = 0; k < K3; ++k) acc = fmaf(up[k], wk[k], acc);
      T3s[s * 4096 + w] = acc;
    }
  }
  // --- T2 ---
  for (int w = tid; w < 1024; w += 512) {
    const int m = w >> 8;
    const int r = w & 255;
    const int wb = (m == 0) ? 11 : 27;
    const float4 u2 = (m == 0)
        ? *(const float4*)(U02 + r * K2)
        : *(const float4*)(U12 + ((m - 1) * 256 + r) * K2);
    T2s[w] = u2.x * wrow[wb] + u2.y * wrow[wb + 1]
           + u2.z * wrow[wb + 2] + u2.w * wrow[wb + 3];
  }
  // --- T1 ---
  if (tid < 64) {
    const int m  = tid >> 4;
    const int i1 = tid & 15;
    T1s[tid] = (m == 0) ? U01[i1] * wrow[15] : U11[(m - 1) * 16 + i1] * wrow[31];
  }
  __syncthreads();

  // --- phase B: lane = node, wave-uniform broadcast T3 reads ---
  const int wave = tid >> 6;
  const int m    = wave & 3;            // output slot
  const int grp  = wave >> 2;           // node group (0/1)
  const int lane = tid & 63;
  const float* T3m = T3s + m * 4096;
  const float* T2m = T2s + m * 256;
  const float* T1m = T1s + m * 16;
  const int total = cnt;

  for (int base = grp * 64; base < total; base += 128) {
    const int idx     = base + lane;
    const bool active = idx < total;
    const int b = nodelist[active ? idx : 0];
    const float* xr = node_feats + ((size_t)b * C_CH + c) * 16;
    float xs[16];                       // static-index only -> registers
    *(float4*)&xs[0]  = ((const float4*)xr)[0];
    *(float4*)&xs[4]  = ((const float4*)xr)[1];
    *(float4*)&xs[8]  = ((const float4*)xr)[2];
    *(float4*)&xs[12] = ((const float4*)xr)[3];
    #pragma unroll
    for (int j = 0; j < 16; ++j) Xl[grp][j][lane] = xs[j];  // lane-consecutive, conflict-free

    float s_tot = 0.f;
    for (int i1 = 0; i1 < 16; ++i1) {
      const float* t3r = T3m + i1 * 256;
      float t2r[16];                    // static-index after unroll -> registers
      *(float4*)&t2r[0]  = ((const float4*)(T2m + i1 * 16))[0];
      *(float4*)&t2r[4]  = ((const float4*)(T2m + i1 * 16))[1];
      *(float4*)&t2r[8]  = ((const float4*)(T2m + i1 * 16))[2];
      *(float4*)&t2r[12] = ((const float4*)(T2m + i1 * 16))[3];
      float s1 = 0.f;
      #pragma unroll
      for (int i2 = 0; i2 < 16; ++i2) {
        const float4 q0 = ((const float4*)(t3r + i2 * 16))[0];  // broadcast
        const float4 q1 = ((const float4*)(t3r + i2 * 16))[1];
        const float4 q2 = ((const float4*)(t3r + i2 * 16))[2];
        const float4 q3 = ((const float4*)(t3r + i2 * 16))[3];
        float d0 = q0.x * xs[0]  + q0.y * xs[1]  + q0.z * xs[2]  + q0.w * xs[3];
        float d1 = q1.x * xs[4]  + q1.y * xs[5]  + q1.z * xs[6]  + q1.w * xs[7];
        float d2 = q2.x * xs[8]  + q2.y * xs[9]  + q2.z * xs[10] + q2.w * xs[11];
        float d3 = q3.x * xs[12] + q3.y * xs[13] + q3.z * xs[14] + q3.w * xs[15];
        const float inner = (d0 + d1) + (d2 + d3);
        s1 = fmaf(inner + t2r[i2], xs[i2], s1);
      }
      const float x1v = Xl[grp][i1][lane];      // same-lane readback (dynamic i1)
      s_tot = fmaf(s1 + T1m[i1], x1v, s_tot);
    }
    if (active)
      feats_out[(size_t)b * 512 + c * 4 + m] = s_tot;
  }
}

__global__ __launch_bounds__(256) void linear_kernel(
    const float* __restrict__ sc,
    const float* __restrict__ lin0,
    const float* __restrict__ lin1,
    float* __restrict__ io)             // d_out, in-place per-row
{
  __shared__ float f[512];              // [c][m]
  const int b   = blockIdx.x;
  const int tid = threadIdx.x;
  const float* row = io + (size_t)b * 512;
  if (tid < 128) ((float4*)f)[tid] = ((const float4*)row)[tid];
  __syncthreads();
  const float inv_sqrt_c = 0.088388347648318447f;   // 1/sqrt(128)
  #pragma unroll
  for (int rep = 0; rep < 2; ++rep) {
    const int o = tid + rep * 256;
    float acc = 0.f;
    if (o < 128) {
      const int fo = o;
      #pragma unroll 4
      for (int ci = 0; ci < 128; ++ci) acc += f[ci * 4] * lin0[ci * 128 + fo];
    } else {
      const int oo = o - 128;
      const int fo = oo / 3;
      const int dd = oo - fo * 3;
      #pragma unroll 4
      for (int ci = 0; ci < 128; ++ci) acc += f[ci * 4 + 1 + dd] * lin1[ci * 128 + fo];
    }
    io[(size_t)b * 512 + o] = acc * inv_sqrt_c + sc[(size_t)b * 512 + o];
  }
}

extern "C" void kernel_launch(void* const* d_in, const int* in_sizes, int n_in,
                              void* d_out, int out_size, void* d_ws, size_t ws_size,
                              hipStream_t stream) {
  const float* node_feats = (const float*)d_in[0];
  const float* sc         = (const float*)d_in[1];
  const float* node_attrs = (const float*)d_in[2];
  const float* U01  = (const float*)d_in[3];
  const float* W01  = (const float*)d_in[4];
  const float* U02  = (const float*)d_in[5];
  const float* W02  = (const float*)d_in[6];
  const float* U03  = (const float*)d_in[7];
  const float* W03  = (const float*)d_in[8];
  const float* lin0 = (const float*)d_in[9];
  const float* U11  = (const float*)d_in[10];
  const float* W11  = (const float*)d_in[11];
  const float* U12  = (const float*)d_in[12];
  const float* W12  = (const float*)d_in[13];
  const float* U13  = (const float*)d_in[14];
  const float* W13  = (const float*)d_in[15];
  const float* lin1 = (const float*)d_in[16];
  float* out = (float*)d_out;

  sym_contract_kernel<<<N_ELEM * C_CH, 512, 0, stream>>>(
      node_feats, node_attrs,
      U03, W03, U02, W02, U01, W01,
      U13, W13, U12, W12, U11, W11, out);
  linear_kernel<<<N_NODES, 256, 0, stream>>>(sc, lin0, lin1, out);
}

// Round 5
// 141.468 us; speedup vs baseline: 2.2502x; 1.2191x over previous
//
#include <hip/hip_runtime.h>

#define N_NODES 1024
#define C_CH    128
#define N_ELEM  10
#define K3      11
#define K2      4

__global__ __launch_bounds__(512) void sym_contract_kernel(
    const float* __restrict__ node_feats,   // [N, C, 16]
    const float* __restrict__ node_attrs,   // [N, 10]
    const float* __restrict__ U03, const float* __restrict__ W03,
    const float* __restrict__ U02, const float* __restrict__ W02,
    const float* __restrict__ U01, const float* __restrict__ W01,
    const float* __restrict__ U13, const float* __restrict__ W13,
    const float* __restrict__ U12, const float* __restrict__ W12,
    const float* __restrict__ U11, const float* __restrict__ W11,
    float* __restrict__ feats_out)          // [N, C*4] pre-linear (= d_out)
{
  __shared__ float T3s[4 * 4096];           // [m][i1][i2][i3] linear; broadcast reads
  __shared__ float T2s[4 * 256];            // [m][i1][i2]
  __shared__ float T1s[4 * 16];             // [m][i1]
  __shared__ float Xl[2][16][64];           // per-lane x stash for dynamic x[i1]
  __shared__ unsigned short nodelist[N_NODES];
  __shared__ float wrow[32];
  __shared__ int cnt;

  const int e   = blockIdx.x / C_CH;
  const int c   = blockIdx.x % C_CH;
  const int tid = threadIdx.x;

  if (tid == 0) cnt = 0;
  if (tid < 32) {
    float v;
    if (tid < 11)       v = W03[(e * K3 + tid) * C_CH + c];
    else if (tid < 15)  v = W02[(e * K2 + (tid - 11)) * C_CH + c];
    else if (tid == 15) v = W01[e * C_CH + c];
    else if (tid < 27)  v = W13[(e * K3 + (tid - 16)) * C_CH + c];
    else if (tid < 31)  v = W12[(e * K2 + (tid - 27)) * C_CH + c];
    else                v = W11[e * C_CH + c];
    wrow[tid] = v;
  }
  __syncthreads();

  // --- node list for this element ---
  for (int b = tid; b < N_NODES; b += 512)
    if (node_attrs[b * N_ELEM + e] > 0.5f) {
      int p = atomicAdd(&cnt, 1);
      nodelist[p] = (unsigned short)b;
    }

  // --- build T3 (all 4 m-slices, linear layout) ---
  for (int s = 0; s < 4; ++s) {
    const int wb = (s == 0) ? 0 : 16;
    float wk[K3];
    #pragma unroll
    for (int k = 0; k < K3; ++k) wk[k] = wrow[wb + k];
    const float* U3 = (s == 0) ? U03 : (U13 + (size_t)(s - 1) * 4096 * K3);
    for (int w = tid; w < 4096; w += 512) {
      const float* up = U3 + (size_t)w * K3;
      float acc = 0.f;
      #pragma unroll
      for (int k = 0; k < K3; ++k) acc = fmaf(up[k], wk[k], acc);
      T3s[s * 4096 + w] = acc;
    }
  }
  // --- T2 ---
  for (int w = tid; w < 1024; w += 512) {
    const int m = w >> 8;
    const int r = w & 255;
    const int wb = (m == 0) ? 11 : 27;
    const float4 u2 = (m == 0)
        ? *(const float4*)(U02 + r * K2)
        : *(const float4*)(U12 + ((m - 1) * 256 + r) * K2);
    T2s[w] = u2.x * wrow[wb] + u2.y * wrow[wb + 1]
           + u2.z * wrow[wb + 2] + u2.w * wrow[wb + 3];
  }
  // --- T1 ---
  if (tid < 64) {
    const int m  = tid >> 4;
    const int i1 = tid & 15;
    T1s[tid] = (m == 0) ? U01[i1] * wrow[15] : U11[(m - 1) * 16 + i1] * wrow[31];
  }
  __syncthreads();

  // --- phase B: lane = node, wave-uniform broadcast T3 reads, pure-FMA chain ---
  const int wave = tid >> 6;
  const int m    = wave & 3;            // output slot
  const int grp  = wave >> 2;           // node group (0/1)
  const int lane = tid & 63;
  const float* T3m = T3s + m * 4096;
  const float* T2m = T2s + m * 256;
  const float* T1m = T1s + m * 16;
  const int total = cnt;

  for (int base = grp * 64; base < total; base += 128) {
    const int idx     = base + lane;
    const bool active = idx < total;
    const int b = nodelist[active ? idx : 0];
    const float* xr = node_feats + ((size_t)b * C_CH + c) * 16;
    float xs[16];                       // static-index only -> registers
    *(float4*)&xs[0]  = ((const float4*)xr)[0];
    *(float4*)&xs[4]  = ((const float4*)xr)[1];
    *(float4*)&xs[8]  = ((const float4*)xr)[2];
    *(float4*)&xs[12] = ((const float4*)xr)[3];
    #pragma unroll
    for (int j = 0; j < 16; ++j) Xl[grp][j][lane] = xs[j];  // lane-consecutive, conflict-free

    float s_tot = 0.f;
    for (int i1 = 0; i1 < 16; ++i1) {
      const float* t3r = T3m + i1 * 256;
      const float* t2p = T2m + i1 * 16;
      float t2r[16];                    // static-index after unroll -> registers
      *(float4*)&t2r[0]  = ((const float4*)t2p)[0];
      *(float4*)&t2r[4]  = ((const float4*)t2p)[1];
      *(float4*)&t2r[8]  = ((const float4*)t2p)[2];
      *(float4*)&t2r[12] = ((const float4*)t2p)[3];
      float s1 = T1m[i1];               // fold +T1 into chain init
      #pragma unroll
      for (int i2 = 0; i2 < 16; ++i2) {
        const float4 q0 = ((const float4*)(t3r + i2 * 16))[0];  // broadcast reads
        const float4 q1 = ((const float4*)(t3r + i2 * 16))[1];
        const float4 q2 = ((const float4*)(t3r + i2 * 16))[2];
        const float4 q3 = ((const float4*)(t3r + i2 * 16))[3];
        float d = t2r[i2];              // fold +T2 into chain init
        d = fmaf(q0.x, xs[0],  d); d = fmaf(q0.y, xs[1],  d);
        d = fmaf(q0.z, xs[2],  d); d = fmaf(q0.w, xs[3],  d);
        d = fmaf(q1.x, xs[4],  d); d = fmaf(q1.y, xs[5],  d);
        d = fmaf(q1.z, xs[6],  d); d = fmaf(q1.w, xs[7],  d);
        d = fmaf(q2.x, xs[8],  d); d = fmaf(q2.y, xs[9],  d);
        d = fmaf(q2.z, xs[10], d); d = fmaf(q2.w, xs[11], d);
        d = fmaf(q3.x, xs[12], d); d = fmaf(q3.y, xs[13], d);
        d = fmaf(q3.z, xs[14], d); d = fmaf(q3.w, xs[15], d);
        s1 = fmaf(d, xs[i2], s1);
      }
      const float x1v = Xl[grp][i1][lane];      // same-lane readback (dynamic i1)
      s_tot = fmaf(s1, x1v, s_tot);
    }
    if (active)
      feats_out[(size_t)b * 512 + c * 4 + m] = s_tot;
  }
}

__global__ __launch_bounds__(256) void linear_kernel(
    const float* __restrict__ sc,
    const float* __restrict__ lin0,
    const float* __restrict__ lin1,
    float* __restrict__ io)             // d_out, in-place per-row
{
  __shared__ float f[512];              // [c][m]
  const int b   = blockIdx.x;
  const int tid = threadIdx.x;
  const float* row = io + (size_t)b * 512;
  if (tid < 128) ((float4*)f)[tid] = ((const float4*)row)[tid];
  __syncthreads();
  const float inv_sqrt_c = 0.088388347648318447f;   // 1/sqrt(128)
  #pragma unroll
  for (int rep = 0; rep < 2; ++rep) {
    const int o = tid + rep * 256;
    float acc = 0.f;
    if (o < 128) {
      const int fo = o;
      #pragma unroll 4
      for (int ci = 0; ci < 128; ++ci) acc = fmaf(f[ci * 4], lin0[ci * 128 + fo], acc);
    } else {
      const int oo = o - 128;
      const int fo = oo / 3;
      const int dd = oo - fo * 3;
      #pragma unroll 4
      for (int ci = 0; ci < 128; ++ci) acc = fmaf(f[ci * 4 + 1 + dd], lin1[ci * 128 + fo], acc);
    }
    io[(size_t)b * 512 + o] = fmaf(acc, inv_sqrt_c, sc[(size_t)b * 512 + o]);
  }
}

extern "C" void kernel_launch(void* const* d_in, const int* in_sizes, int n_in,
                              void* d_out, int out_size, void* d_ws, size_t ws_size,
                              hipStream_t stream) {
  const float* node_feats = (const float*)d_in[0];
  const float* sc         = (const float*)d_in[1];
  const float* node_attrs = (const float*)d_in[2];
  const float* U01  = (const float*)d_in[3];
  const float* W01  = (const float*)d_in[4];
  const float* U02  = (const float*)d_in[5];
  const float* W02  = (const float*)d_in[6];
  const float* U03  = (const float*)d_in[7];
  const float* W03  = (const float*)d_in[8];
  const float* lin0 = (const float*)d_in[9];
  const float* U11  = (const float*)d_in[10];
  const float* W11  = (const float*)d_in[11];
  const float* U12  = (const float*)d_in[12];
  const float* W12  = (const float*)d_in[13];
  const float* U13  = (const float*)d_in[14];
  const float* W13  = (const float*)d_in[15];
  const float* lin1 = (const float*)d_in[16];
  float* out = (float*)d_out;

  sym_contract_kernel<<<N_ELEM * C_CH, 512, 0, stream>>>(
      node_feats, node_attrs,
      U03, W03, U02, W02, U01, W01,
      U13, W13, U12, W12, U11, W11, out);
  linear_kernel<<<N_NODES, 256, 0, stream>>>(sc, lin0, lin1, out);
}